// Round 3
// baseline (1391.047 us; speedup 1.0000x reference)
//
#include <hip/hip_runtime.h>
#include <stdint.h>

typedef unsigned short u16;
typedef unsigned int u32;
typedef unsigned long long u64;
typedef __attribute__((ext_vector_type(8))) short short8;   // 8 x bf16 (4 VGPRs)
typedef __attribute__((ext_vector_type(4))) float f32x4;

#define DEVI static __device__ __forceinline__

#define S_LEN 2048
#define DMODEL 1024
#define NHEAD 16
#define DK 64
#define NEG_INF (-__builtin_inff())
// u = bitcast((bits>>9)|0x3f800000)-1; boundary 0.9f = 7549747/2^23
// keep:   u > 0.9  <=> (bits>>9) > 7549747  <=> bits >= 7549748*512
// dropout:u < 0.9  <=> (bits>>9) < 7549747  <=> bits <  7549747*512
#define KEEPC 3865470976u
#define DROPC 3865470464u

DEVI u16 f2bf(float f) {
  u32 u = __builtin_bit_cast(u32, f);
  u32 r = u + 0x7fffu + ((u >> 16) & 1u);   // RNE
  return (u16)(r >> 16);
}

DEVI short8 cvt8(float4 a, float4 b) {
  short8 r;
  r[0] = (short)f2bf(a.x); r[1] = (short)f2bf(a.y);
  r[2] = (short)f2bf(a.z); r[3] = (short)f2bf(a.w);
  r[4] = (short)f2bf(b.x); r[5] = (short)f2bf(b.y);
  r[6] = (short)f2bf(b.z); r[7] = (short)f2bf(b.w);
  return r;
}

// JAX threefry2x32 (20 rounds), partitionable draw: key (0,key), ctr (0,i),
// bits = o0 ^ o1. Specialized for K0=0: injections become compile-time consts.
DEVI u32 tf_bits(u32 key, u32 i) {
  const u32 K2 = key ^ 0x1BD11BDAu;
  u32 x0 = 0u, x1 = i + key;
#define TFR(r) { x0 += x1; x1 = __builtin_rotateleft32(x1, r); x1 ^= x0; }
  TFR(13) TFR(15) TFR(26) TFR(6)  x0 += key; x1 += K2 + 1u;
  TFR(17) TFR(29) TFR(16) TFR(24) x0 += K2;  x1 += 2u;
  TFR(13) TFR(15) TFR(26) TFR(6)  /*x0+=0*/  x1 += key + 3u;
  TFR(17) TFR(29) TFR(16) TFR(24) x0 += key; x1 += K2 + 4u;
  TFR(13) TFR(15) TFR(26) TFR(6)  x0 += K2;  x1 += 5u;
#undef TFR
  return x0 ^ x1;
}

DEVI u32 mbcnt64(u64 m) {
  return __builtin_amdgcn_mbcnt_hi((u32)(m >> 32),
         __builtin_amdgcn_mbcnt_lo((u32)m, 0u));
}

// ---------------- RNG: keep + dropout bit masks (wave-collective) ----------------
// Word layout: word = ((bh*32 + k/64)*2048 + q)*2 + ((k/32)&1), bit = k&31.
// Wave W handles (bh = W>>10, kth = (W>>5)&31, q0 = (W&31)*64), 64 q values.
// Per group: lane j computes draw i = (bh*2048+q)*2048 + kth*64 + j; keep bits
// packed with one ballot. Dropout draws (kept positions only, ~10%) go through
// a per-wave LDS compaction queue and are drained 64-at-a-time at full lane
// utilization, scattering bits via global_atomic_or (dropw pre-zeroed).
__global__ __launch_bounds__(256) void rng_kernel(u32* __restrict__ keepw, u32* __restrict__ dropw)
{
  __shared__ u32 qbuf[4][128];
  const int wv = threadIdx.x >> 6, lane = threadIdx.x & 63;
  const u32 W = blockIdx.x * 4u + (u32)wv;                 // < 65536
  const u32 q0 = (W & 31u) * 64u, kth = (W >> 5) & 31u, bh = W >> 10;

  u32 ivar = (bh * 2048u + q0) * 2048u + kth * 64u + (u32)lane;
  u32 widx = (bh * 32u + kth) * 4096u + q0 * 2u;
  u32 wpos = 0, rpos = 0;

  for (int g = 0; g < 64; ++g) {
    const u32 bits = tf_bits(42u, ivar);
    const bool kept = (bits >= KEEPC);
    const u64 keep = __ballot(kept);
    if (lane == 0) *(uint2*)(keepw + widx) = make_uint2((u32)keep, (u32)(keep >> 32));
    const u32 before = mbcnt64(keep);
    if (kept) qbuf[wv][(wpos + before) & 127u] = ivar;
    wpos += (u32)__popcll(keep);
    if (wpos - rpos >= 64u) {                              // wave-uniform branch
      const u32 idx = qbuf[wv][(rpos + (u32)lane) & 127u];
      const u32 db = tf_bits(7u, idx);
      const u32 kk = idx & 2047u, qq = (idx >> 11) & 2047u, bb = idx >> 22;
      const u32 word = (bb * 32u + (kk >> 6)) * 4096u + qq * 2u + ((kk >> 5) & 1u);
      if (db < DROPC) atomicOr(dropw + word, 1u << (kk & 31u));
      rpos += 64u;
    }
    ivar += 2048u; widx += 2u;
  }
  const u32 rem = wpos - rpos;                             // < 64
  if ((u32)lane < rem) {
    const u32 idx = qbuf[wv][(rpos + (u32)lane) & 127u];
    const u32 db = tf_bits(7u, idx);
    const u32 kk = idx & 2047u, qq = (idx >> 11) & 2047u, bb = idx >> 22;
    const u32 word = (bb * 32u + (kk >> 6)) * 4096u + qq * 2u + ((kk >> 5) & 1u);
    if (db < DROPC) atomicOr(dropw + word, 1u << (kk & 31u));
  }
}

// ---------------- QKV projection GEMM (x @ W.T + b), fp32 in, bf16 MFMA ----------------
// 64x64 tile / block, 4 waves (2x2), each wave 32x32 via 4 C-frags.
// LDS frag-major: chunk c = fragblk*64+lane holds T[row=fragblk*16+(lane&15)][k=(lane>>4)*8..+7]
__global__ __launch_bounds__(256) void proj_kernel(
    const float* __restrict__ Xq, const float* __restrict__ Xk, const float* __restrict__ Xv,
    const float* __restrict__ Wq, const float* __restrict__ Wk, const float* __restrict__ Wv,
    const float* __restrict__ bq, const float* __restrict__ bk, const float* __restrict__ bv,
    u16* __restrict__ Qo, u16* __restrict__ Ko, u16* __restrict__ Vto)
{
  const int z = blockIdx.z;
  const float* X = (z == 0) ? Xq : (z == 1) ? Xk : Xv;
  const float* W = (z == 0) ? Wq : (z == 1) ? Wk : Wv;
  const float* bias = (z == 0) ? bq : (z == 1) ? bk : bv;
  const int m0 = blockIdx.x * 64, n0 = blockIdx.y * 64;
  const int tid = threadIdx.x, w = tid >> 6, lane = tid & 63, l = lane & 15, quad = lane >> 4;

  __shared__ __align__(16) u16 lsA[2048], lsB[2048];

  const int srow = tid >> 2, skp = tid & 3;
  const int sc = ((srow >> 4) * 64 + skp * 16 + (srow & 15)) * 8;
  const float* gA = X + (u32)(m0 + srow) * DMODEL + skp * 8;
  const float* gB = W + (u32)(n0 + srow) * DMODEL + skp * 8;

  f32x4 acc[2][2] = {};
  const int mh = (w >> 1) * 2, nh = (w & 1) * 2;

  for (int k0 = 0; k0 < DMODEL; k0 += 32) {
    short8 av  = cvt8(*(const float4*)(gA + k0), *(const float4*)(gA + k0 + 4));
    short8 bv8 = cvt8(*(const float4*)(gB + k0), *(const float4*)(gB + k0 + 4));
    __syncthreads();
    *(short8*)(lsA + sc) = av;
    *(short8*)(lsB + sc) = bv8;
    __syncthreads();
    short8 a0 = *(const short8*)(lsA + ((mh + 0) * 64 + lane) * 8);
    short8 a1 = *(const short8*)(lsA + ((mh + 1) * 64 + lane) * 8);
    short8 b0 = *(const short8*)(lsB + ((nh + 0) * 64 + lane) * 8);
    short8 b1 = *(const short8*)(lsB + ((nh + 1) * 64 + lane) * 8);
    acc[0][0] = __builtin_amdgcn_mfma_f32_16x16x32_bf16(a0, b0, acc[0][0], 0, 0, 0);
    acc[0][1] = __builtin_amdgcn_mfma_f32_16x16x32_bf16(a0, b1, acc[0][1], 0, 0, 0);
    acc[1][0] = __builtin_amdgcn_mfma_f32_16x16x32_bf16(a1, b0, acc[1][0], 0, 0, 0);
    acc[1][1] = __builtin_amdgcn_mfma_f32_16x16x32_bf16(a1, b1, acc[1][1], 0, 0, 0);
  }

  #pragma unroll
  for (int ma = 0; ma < 2; ++ma) {
    #pragma unroll
    for (int nb = 0; nb < 2; ++nb) {
      const int n = n0 + (nh + nb) * 16 + l;
      const float bval = bias[n];
      const int h = n >> 6, d = n & 63;
      #pragma unroll
      for (int r = 0; r < 4; ++r) {
        const int m = m0 + (mh + ma) * 16 + quad * 4 + r;
        float val = acc[ma][nb][r] + bval;
        if (z == 0) val *= 0.125f;              // fold 1/sqrt(dk) into Q
        const int b = m >> 11, s = m & 2047;
        if (z == 0)      Qo [((u32)(b * NHEAD + h) * S_LEN + s) * DK + d] = f2bf(val);
        else if (z == 1) Ko [((u32)(b * NHEAD + h) * S_LEN + s) * DK + d] = f2bf(val);
        else             Vto[((u32)(b * NHEAD + h) * DK + d) * S_LEN + s] = f2bf(val); // V transposed
      }
    }
  }
}

// ---------------- flash attention with sparsity mask + dropout ----------------
__global__ __launch_bounds__(256) void attn_kernel(
    const u16* __restrict__ Qs, const u16* __restrict__ Ks, const u16* __restrict__ Vts,
    const u32* __restrict__ keepw, const u32* __restrict__ dropw,
    u16* __restrict__ ctx)
{
  const int qb = blockIdx.x, bh = blockIdx.y;
  const int tid = threadIdx.x, w = tid >> 6, lane = tid & 63, l = lane & 15, quad = lane >> 4;

  __shared__ __align__(16) u16 Kf[4096];        // 8 frags x 64 lanes x 8 bf16
  __shared__ __align__(16) u16 Vf[4096];
  __shared__ __align__(16) u16 Pf[4][1024];     // per-wave P (2 A-frags)
  __shared__ u32 keepL[128], dropL[128];

  // Q A-frags, preloaded (Q pre-scaled by 1/8)
  const int qrow0 = qb * 64 + w * 16;
  const u32 qbase = (u32)(bh * S_LEN + qrow0 + l) * DK + quad * 8;
  const short8 qa0 = *(const short8*)(Qs + qbase);
  const short8 qa1 = *(const short8*)(Qs + qbase + 32);

  f32x4 o[4] = {};
  float mr[4] = {NEG_INF, NEG_INF, NEG_INF, NEG_INF};
  float lr[4] = {0.f, 0.f, 0.f, 0.f};

  // staging maps (2 chunks per thread per tile), globally coalesced
  const int tA = tid, tB = tid + 256;
  const int keyA = tA >> 3, dpA = tA & 7;
  const int kcA = (((dpA >> 2) * 4 + (keyA >> 4)) * 64 + (dpA & 3) * 16 + (keyA & 15)) * 8;
  const u32 gkA = (u32)(bh * S_LEN + keyA) * DK + dpA * 8;
  const int keyB = tB >> 3, dpB = tB & 7;
  const int kcB = (((dpB >> 2) * 4 + (keyB >> 4)) * 64 + (dpB & 3) * 16 + (keyB & 15)) * 8;
  const u32 gkB = (u32)(bh * S_LEN + keyB) * DK + dpB * 8;
  const int vcA = (((keyA >> 4) * 2 + (dpA >> 2)) * 64 + (dpA & 3) * 16 + (keyA & 15)) * 8;
  const u32 gvA = (u32)(bh * DK + keyA) * S_LEN + dpA * 8;   // keyA plays "d" role here
  const int vcB = (((keyB >> 4) * 2 + (dpB >> 2)) * 64 + (dpB & 3) * 16 + (keyB & 15)) * 8;
  const u32 gvB = (u32)(bh * DK + keyB) * S_LEN + dpB * 8;

  for (int kt = 0; kt < 32; ++kt) {
    const u32 ko = (u32)kt * 64u;
    short8 k0v = *(const short8*)(Ks + gkA + ko * DK);
    short8 k1v = *(const short8*)(Ks + gkB + ko * DK);
    short8 v0v = *(const short8*)(Vts + gvA + ko);
    short8 v1v = *(const short8*)(Vts + gvB + ko);
    const u32 mwi = (u32)(bh * 32 + kt) * 4096u + (u32)qb * 128u;
    u32 mw = (tid < 128) ? keepw[mwi + tid] : dropw[mwi + tid - 128];
    __syncthreads();
    *(short8*)(Kf + kcA) = k0v;
    *(short8*)(Kf + kcB) = k1v;
    *(short8*)(Vf + vcA) = v0v;
    *(short8*)(Vf + vcB) = v1v;
    if (tid < 128) keepL[tid] = mw; else dropL[tid - 128] = mw;
    __syncthreads();

    // S = Q K^T (16q x 64keys per wave)
    f32x4 sc4[4];
    #pragma unroll
    for (int nc = 0; nc < 4; ++nc) {
      short8 kb0 = *(const short8*)(Kf + (nc * 64 + lane) * 8);
      short8 kb1 = *(const short8*)(Kf + ((4 + nc) * 64 + lane) * 8);
      f32x4 zz = {0.f, 0.f, 0.f, 0.f};
      zz = __builtin_amdgcn_mfma_f32_16x16x32_bf16(qa0, kb0, zz, 0, 0, 0);
      sc4[nc] = __builtin_amdgcn_mfma_f32_16x16x32_bf16(qa1, kb1, zz, 0, 0, 0);
    }

    u16* pw = Pf[w];
    #pragma unroll
    for (int r = 0; r < 4; ++r) {
      const int qq = w * 16 + quad * 4 + r;
      const u32 kwx = keepL[qq * 2], kwy = keepL[qq * 2 + 1];
      const u32 dwx = dropL[qq * 2], dwy = dropL[qq * 2 + 1];
      float v0 = ((kwx >> l) & 1u)        ? sc4[0][r] : NEG_INF;
      float v1 = ((kwx >> (16 + l)) & 1u) ? sc4[1][r] : NEG_INF;
      float v2 = ((kwy >> l) & 1u)        ? sc4[2][r] : NEG_INF;
      float v3 = ((kwy >> (16 + l)) & 1u) ? sc4[3][r] : NEG_INF;
      float mx = fmaxf(fmaxf(v0, v1), fmaxf(v2, v3));
      mx = fmaxf(mx, __shfl_xor(mx, 1));
      mx = fmaxf(mx, __shfl_xor(mx, 2));
      mx = fmaxf(mx, __shfl_xor(mx, 4));
      mx = fmaxf(mx, __shfl_xor(mx, 8));
      const float mn = fmaxf(mr[r], mx);
      const float alpha = (mn == NEG_INF) ? 1.f : __expf(mr[r] - mn);
      mr[r] = mn;
      const float p0 = (v0 == NEG_INF) ? 0.f : __expf(v0 - mn);
      const float p1 = (v1 == NEG_INF) ? 0.f : __expf(v1 - mn);
      const float p2 = (v2 == NEG_INF) ? 0.f : __expf(v2 - mn);
      const float p3 = (v3 == NEG_INF) ? 0.f : __expf(v3 - mn);
      float rs = p0 + p1 + p2 + p3;
      rs += __shfl_xor(rs, 1);
      rs += __shfl_xor(rs, 2);
      rs += __shfl_xor(rs, 4);
      rs += __shfl_xor(rs, 8);
      lr[r] = alpha * lr[r] + rs;
      o[0][r] = o[0][r] * alpha; o[1][r] = o[1][r] * alpha;
      o[2][r] = o[2][r] * alpha; o[3][r] = o[3][r] * alpha;
      // dropout (denominator uses undropped p; numerator uses p*dbit/0.9)
      const float pd0 = ((dwx >> l) & 1u)        ? p0 * (1.f / 0.9f) : 0.f;
      const float pd1 = ((dwx >> (16 + l)) & 1u) ? p1 * (1.f / 0.9f) : 0.f;
      const float pd2 = ((dwy >> l) & 1u)        ? p2 * (1.f / 0.9f) : 0.f;
      const float pd3 = ((dwy >> (16 + l)) & 1u) ? p3 * (1.f / 0.9f) : 0.f;
      // write P in A-frag layout: elem(m=qrow, k=key) -> chunk (k>>5)*64 + ((k>>3)&3)*16 + m
      const int hi = l >> 3, bq_ = quad * 4 + r, j = l & 7;
      pw[((hi) * 16 + bq_) * 8 + j]            = f2bf(pd0);   // keys  0..15
      pw[((2 + hi) * 16 + bq_) * 8 + j]        = f2bf(pd1);   // keys 16..31
      pw[(64 + hi * 16 + bq_) * 8 + j]         = f2bf(pd2);   // keys 32..47
      pw[(64 + (2 + hi) * 16 + bq_) * 8 + j]   = f2bf(pd3);   // keys 48..63
    }
    // same-wave LDS round-trip: read P as A-frags
    short8 pa0 = *(const short8*)(Pf[w] + lane * 8);
    short8 pa1 = *(const short8*)(Pf[w] + (64 + lane) * 8);
    #pragma unroll
    for (int nd = 0; nd < 4; ++nd) {
      short8 vb0 = *(const short8*)(Vf + ((nd * 2 + 0) * 64 + lane) * 8);
      short8 vb1 = *(const short8*)(Vf + ((nd * 2 + 1) * 64 + lane) * 8);
      o[nd] = __builtin_amdgcn_mfma_f32_16x16x32_bf16(pa0, vb0, o[nd], 0, 0, 0);
      o[nd] = __builtin_amdgcn_mfma_f32_16x16x32_bf16(pa1, vb1, o[nd], 0, 0, 0);
    }
  }

  const int b = bh >> 4, h = bh & 15;
  #pragma unroll
  for (int r = 0; r < 4; ++r) {
    const float inv = 1.f / lr[r];
    const int qrow = qb * 64 + w * 16 + quad * 4 + r;
    const u32 ob = (u32)(b * S_LEN + qrow) * DMODEL + h * DK;
    ctx[ob + 0  + l] = f2bf(o[0][r] * inv);
    ctx[ob + 16 + l] = f2bf(o[1][r] * inv);
    ctx[ob + 32 + l] = f2bf(o[2][r] * inv);
    ctx[ob + 48 + l] = f2bf(o[3][r] * inv);
  }
}

// ---------------- output projection (ctx @ Wo.T + bo), bf16 A, fp32 B-in, fp32 out ----------------
__global__ __launch_bounds__(256) void oproj_kernel(
    const u16* __restrict__ X, const float* __restrict__ W, const float* __restrict__ bias,
    float* __restrict__ out)
{
  const int m0 = blockIdx.x * 64, n0 = blockIdx.y * 64;
  const int tid = threadIdx.x, w = tid >> 6, lane = tid & 63, l = lane & 15, quad = lane >> 4;

  __shared__ __align__(16) u16 lsA[2048], lsB[2048];

  const int srow = tid >> 2, skp = tid & 3;
  const int sc = ((srow >> 4) * 64 + skp * 16 + (srow & 15)) * 8;
  const u16*  gA = X + (u32)(m0 + srow) * DMODEL + skp * 8;
  const float* gB = W + (u32)(n0 + srow) * DMODEL + skp * 8;

  f32x4 acc[2][2] = {};
  const int mh = (w >> 1) * 2, nh = (w & 1) * 2;

  for (int k0 = 0; k0 < DMODEL; k0 += 32) {
    short8 av  = *(const short8*)(gA + k0);
    short8 bv8 = cvt8(*(const float4*)(gB + k0), *(const float4*)(gB + k0 + 4));
    __syncthreads();
    *(short8*)(lsA + sc) = av;
    *(short8*)(lsB + sc) = bv8;
    __syncthreads();
    short8 a0 = *(const short8*)(lsA + ((mh + 0) * 64 + lane) * 8);
    short8 a1 = *(const short8*)(lsA + ((mh + 1) * 64 + lane) * 8);
    short8 b0 = *(const short8*)(lsB + ((nh + 0) * 64 + lane) * 8);
    short8 b1 = *(const short8*)(lsB + ((nh + 1) * 64 + lane) * 8);
    acc[0][0] = __builtin_amdgcn_mfma_f32_16x16x32_bf16(a0, b0, acc[0][0], 0, 0, 0);
    acc[0][1] = __builtin_amdgcn_mfma_f32_16x16x32_bf16(a0, b1, acc[0][1], 0, 0, 0);
    acc[1][0] = __builtin_amdgcn_mfma_f32_16x16x32_bf16(a1, b0, acc[1][0], 0, 0, 0);
    acc[1][1] = __builtin_amdgcn_mfma_f32_16x16x32_bf16(a1, b1, acc[1][1], 0, 0, 0);
  }

  #pragma unroll
  for (int ma = 0; ma < 2; ++ma) {
    #pragma unroll
    for (int nb = 0; nb < 2; ++nb) {
      const int n = n0 + (nh + nb) * 16 + l;
      const float bval = bias[n];
      #pragma unroll
      for (int r = 0; r < 4; ++r) {
        const int m = m0 + (mh + ma) * 16 + quad * 4 + r;
        out[(u32)m * DMODEL + n] = acc[ma][nb][r] + bval;
      }
    }
  }
}

extern "C" void kernel_launch(void* const* d_in, const int* in_sizes, int n_in,
                              void* d_out, int out_size, void* d_ws, size_t ws_size,
                              hipStream_t stream) {
  (void)in_sizes; (void)n_in; (void)out_size; (void)ws_size;
  const float* q  = (const float*)d_in[0];
  const float* k  = (const float*)d_in[1];
  const float* v  = (const float*)d_in[2];
  const float* Wq = (const float*)d_in[3];
  const float* bq = (const float*)d_in[4];
  const float* Wk = (const float*)d_in[5];
  const float* bk = (const float*)d_in[6];
  const float* Wv = (const float*)d_in[7];
  const float* bv = (const float*)d_in[8];
  const float* Wo = (const float*)d_in[9];
  const float* bo = (const float*)d_in[10];

  char* ws = (char*)d_ws;
  u16* Qs   = (u16*)(ws);                 // [bh][s][dk] bf16, pre-scaled 1/8 (16 MB)
  u16* Ks   = (u16*)(ws + 16777216);      // [bh][s][dk]
  u16* Vts  = (u16*)(ws + 33554432);      // [bh][dk][s]  (transposed)
  u16* ctx  = (u16*)(ws + 50331648);      // [b][s][h*dk]
  u32* keepw = (u32*)(ws + 67108864);     // 32 MB bit mask
  u32* dropw = (u32*)(ws + 100663296);    // 32 MB bit mask  (total ws: 128 MB)

  hipMemsetAsync(dropw, 0, 33554432, stream);   // atomics OR into dropw
  rng_kernel<<<dim3(16384), 256, 0, stream>>>(keepw, dropw);
  proj_kernel<<<dim3(128, 16, 3), 256, 0, stream>>>(q, k, v, Wq, Wk, Wv,
                                                    bq, bk, bv, Qs, Ks, Vts);
  attn_kernel<<<dim3(32, 64), 256, 0, stream>>>(Qs, Ks, Vts, keepw, dropw, ctx);
  oproj_kernel<<<dim3(128, 16), 256, 0, stream>>>(ctx, Wo, bo, (float*)d_out);
}

// Round 4
// 1175.512 us; speedup vs baseline: 1.1834x; 1.1834x over previous
//
#include <hip/hip_runtime.h>
#include <stdint.h>

typedef unsigned short u16;
typedef unsigned int u32;
typedef __attribute__((ext_vector_type(8))) short short8;   // 8 x bf16 (4 VGPRs)
typedef __attribute__((ext_vector_type(4))) float f32x4;

#define DEVI static __device__ __forceinline__

#define S_LEN 2048
#define DMODEL 1024
#define NHEAD 16
#define DK 64
#define NEG_INF (-__builtin_inff())
// u = bitcast((bits>>9)|0x3f800000)-1; boundary 0.9f = 7549747/2^23
// keep:   u > 0.9  <=> bits >= 7549748*512
// dropout keep: u < 0.9  <=> bits <  7549747*512
#define KEEPC 3865470976u
#define DROPC 3865470464u

DEVI u16 f2bf(float f) {
  u32 u = __builtin_bit_cast(u32, f);
  u32 r = u + 0x7fffu + ((u >> 16) & 1u);   // RNE
  return (u16)(r >> 16);
}

DEVI short8 cvt8(float4 a, float4 b) {
  short8 r;
  r[0] = (short)f2bf(a.x); r[1] = (short)f2bf(a.y);
  r[2] = (short)f2bf(a.z); r[3] = (short)f2bf(a.w);
  r[4] = (short)f2bf(b.x); r[5] = (short)f2bf(b.y);
  r[6] = (short)f2bf(b.z); r[7] = (short)f2bf(b.w);
  return r;
}

// JAX threefry2x32 (20 rounds), partitionable draw (default since jax 0.4.36):
// key (0,key), ctr (0,i), bits = o0 ^ o1. key is compile-time const at call
// sites -> K2 and injections fold. Validated bit-exact in rounds 2/3.
DEVI u32 tf_bits(u32 key, u32 i) {
  const u32 K2 = key ^ 0x1BD11BDAu;
  u32 x0 = 0u, x1 = i + key;
#define TFR(r) { x0 += x1; x1 = __builtin_rotateleft32(x1, r); x1 ^= x0; }
  TFR(13) TFR(15) TFR(26) TFR(6)  x0 += key; x1 += K2 + 1u;
  TFR(17) TFR(29) TFR(16) TFR(24) x0 += K2;  x1 += 2u;
  TFR(13) TFR(15) TFR(26) TFR(6)  /*x0+=0*/  x1 += key + 3u;
  TFR(17) TFR(29) TFR(16) TFR(24) x0 += key; x1 += K2 + 4u;
  TFR(13) TFR(15) TFR(26) TFR(6)  x0 += K2;  x1 += 5u;
#undef TFR
  return x0 ^ x1;
}

// ---------------- QKV projection GEMM (x @ W.T + b), fp32 in, bf16 MFMA ----------------
// 64x64 tile / block, 4 waves (2x2), each wave 32x32 via 4 C-frags.
// LDS frag-major: chunk c = fragblk*64+lane holds T[row=fragblk*16+(lane&15)][k=(lane>>4)*8..+7]
__global__ __launch_bounds__(256) void proj_kernel(
    const float* __restrict__ Xq, const float* __restrict__ Xk, const float* __restrict__ Xv,
    const float* __restrict__ Wq, const float* __restrict__ Wk, const float* __restrict__ Wv,
    const float* __restrict__ bq, const float* __restrict__ bk, const float* __restrict__ bv,
    u16* __restrict__ Qo, u16* __restrict__ Ko, u16* __restrict__ Vto)
{
  const int z = blockIdx.z;
  const float* X = (z == 0) ? Xq : (z == 1) ? Xk : Xv;
  const float* W = (z == 0) ? Wq : (z == 1) ? Wk : Wv;
  const float* bias = (z == 0) ? bq : (z == 1) ? bk : bv;
  const int m0 = blockIdx.x * 64, n0 = blockIdx.y * 64;
  const int tid = threadIdx.x, w = tid >> 6, lane = tid & 63, l = lane & 15, quad = lane >> 4;

  __shared__ __align__(16) u16 lsA[2048], lsB[2048];

  const int srow = tid >> 2, skp = tid & 3;
  const int sc = ((srow >> 4) * 64 + skp * 16 + (srow & 15)) * 8;
  const float* gA = X + (u32)(m0 + srow) * DMODEL + skp * 8;
  const float* gB = W + (u32)(n0 + srow) * DMODEL + skp * 8;

  f32x4 acc[2][2] = {};
  const int mh = (w >> 1) * 2, nh = (w & 1) * 2;

  for (int k0 = 0; k0 < DMODEL; k0 += 32) {
    short8 av  = cvt8(*(const float4*)(gA + k0), *(const float4*)(gA + k0 + 4));
    short8 bv8 = cvt8(*(const float4*)(gB + k0), *(const float4*)(gB + k0 + 4));
    __syncthreads();
    *(short8*)(lsA + sc) = av;
    *(short8*)(lsB + sc) = bv8;
    __syncthreads();
    short8 a0 = *(const short8*)(lsA + ((mh + 0) * 64 + lane) * 8);
    short8 a1 = *(const short8*)(lsA + ((mh + 1) * 64 + lane) * 8);
    short8 b0 = *(const short8*)(lsB + ((nh + 0) * 64 + lane) * 8);
    short8 b1 = *(const short8*)(lsB + ((nh + 1) * 64 + lane) * 8);
    acc[0][0] = __builtin_amdgcn_mfma_f32_16x16x32_bf16(a0, b0, acc[0][0], 0, 0, 0);
    acc[0][1] = __builtin_amdgcn_mfma_f32_16x16x32_bf16(a0, b1, acc[0][1], 0, 0, 0);
    acc[1][0] = __builtin_amdgcn_mfma_f32_16x16x32_bf16(a1, b0, acc[1][0], 0, 0, 0);
    acc[1][1] = __builtin_amdgcn_mfma_f32_16x16x32_bf16(a1, b1, acc[1][1], 0, 0, 0);
  }

  #pragma unroll
  for (int ma = 0; ma < 2; ++ma) {
    #pragma unroll
    for (int nb = 0; nb < 2; ++nb) {
      const int n = n0 + (nh + nb) * 16 + l;
      const float bval = bias[n];
      const int h = n >> 6, d = n & 63;
      #pragma unroll
      for (int r = 0; r < 4; ++r) {
        const int m = m0 + (mh + ma) * 16 + quad * 4 + r;
        float val = acc[ma][nb][r] + bval;
        if (z == 0) val *= 0.125f;              // fold 1/sqrt(dk) into Q
        const int b = m >> 11, s = m & 2047;
        if (z == 0)      Qo [((u32)(b * NHEAD + h) * S_LEN + s) * DK + d] = f2bf(val);
        else if (z == 1) Ko [((u32)(b * NHEAD + h) * S_LEN + s) * DK + d] = f2bf(val);
        else             Vto[((u32)(b * NHEAD + h) * DK + d) * S_LEN + s] = f2bf(val); // V transposed
      }
    }
  }
}

// ---------------- flash attention with INLINE threefry mask + dropout ----------------
// Masks are generated per-lane in exactly the MFMA C-layout positions this lane
// owns: rows quad*4+r, cols c*16+(lane&15). Draw index i = (bh*2048+q)*2048+k.
// Bit s = c*4+r in m16/d16. No mask memory traffic, no cross-lane machinery.
__global__ __launch_bounds__(256) void attn_kernel(
    const u16* __restrict__ Qs, const u16* __restrict__ Ks, const u16* __restrict__ Vts,
    u16* __restrict__ ctx)
{
  const int qb = blockIdx.x, bh = blockIdx.y;
  const int tid = threadIdx.x, w = tid >> 6, lane = tid & 63, l = lane & 15, quad = lane >> 4;

  __shared__ __align__(16) u16 Kf[4096];        // 8 frags x 64 lanes x 8 bf16
  __shared__ __align__(16) u16 Vf[4096];
  __shared__ __align__(16) u16 Pf[4][1024];     // per-wave P (2 A-frags)

  // Q A-frags, preloaded (Q pre-scaled by 1/8)
  const int qrow0 = qb * 64 + w * 16;
  const u32 qbase = (u32)(bh * S_LEN + qrow0 + l) * DK + quad * 8;
  const short8 qa0 = *(const short8*)(Qs + qbase);
  const short8 qa1 = *(const short8*)(Qs + qbase + 32);

  // per-lane RNG base: rows start at qrow0+quad*4, col offset l (within tile)
  u32 ibase = ((u32)bh * 2048u + (u32)(qrow0 + quad * 4)) * 2048u + (u32)l;

  f32x4 o[4] = {};
  float mr[4] = {NEG_INF, NEG_INF, NEG_INF, NEG_INF};
  float lr[4] = {0.f, 0.f, 0.f, 0.f};

  // staging maps (2 chunks per thread per tile), globally coalesced
  const int tA = tid, tB = tid + 256;
  const int keyA = tA >> 3, dpA = tA & 7;
  const int kcA = (((dpA >> 2) * 4 + (keyA >> 4)) * 64 + (dpA & 3) * 16 + (keyA & 15)) * 8;
  const u32 gkA = (u32)(bh * S_LEN + keyA) * DK + dpA * 8;
  const int keyB = tB >> 3, dpB = tB & 7;
  const int kcB = (((dpB >> 2) * 4 + (keyB >> 4)) * 64 + (dpB & 3) * 16 + (keyB & 15)) * 8;
  const u32 gkB = (u32)(bh * S_LEN + keyB) * DK + dpB * 8;
  const int vcA = (((keyA >> 4) * 2 + (dpA >> 2)) * 64 + (dpA & 3) * 16 + (keyA & 15)) * 8;
  const u32 gvA = (u32)(bh * DK + keyA) * S_LEN + dpA * 8;   // keyA plays "d" role here
  const int vcB = (((keyB >> 4) * 2 + (dpB >> 2)) * 64 + (dpB & 3) * 16 + (keyB & 15)) * 8;
  const u32 gvB = (u32)(bh * DK + keyB) * S_LEN + dpB * 8;

  for (int kt = 0; kt < 32; ++kt) {
    const u32 ko = (u32)kt * 64u;
    short8 k0v = *(const short8*)(Ks + gkA + ko * DK);
    short8 k1v = *(const short8*)(Ks + gkB + ko * DK);
    short8 v0v = *(const short8*)(Vts + gvA + ko);
    short8 v1v = *(const short8*)(Vts + gvB + ko);

    // ---- inline RNG: 16 independent keep draws (ILP), then sparse dropout ----
    u32 m16 = 0;
    #pragma unroll
    for (int c = 0; c < 4; ++c) {
      #pragma unroll
      for (int r = 0; r < 4; ++r) {
        m16 |= (u32)(tf_bits(42u, ibase + (u32)(r * 2048 + c * 16)) >= KEEPC) << (c * 4 + r);
      }
    }
    u32 d16 = 0, mm = m16;
    while (mm) {
      const u32 s = (u32)__builtin_ctz(mm); mm &= mm - 1u;
      const u32 ii = ibase + (s & 3u) * 2048u + (s >> 2) * 16u;
      d16 |= (u32)(tf_bits(7u, ii) < DROPC) << s;
    }
    ibase += 64u;

    __syncthreads();
    *(short8*)(Kf + kcA) = k0v;
    *(short8*)(Kf + kcB) = k1v;
    *(short8*)(Vf + vcA) = v0v;
    *(short8*)(Vf + vcB) = v1v;
    __syncthreads();

    // S = Q K^T (16q x 64keys per wave)
    f32x4 sc4[4];
    #pragma unroll
    for (int nc = 0; nc < 4; ++nc) {
      short8 kb0 = *(const short8*)(Kf + (nc * 64 + lane) * 8);
      short8 kb1 = *(const short8*)(Kf + ((4 + nc) * 64 + lane) * 8);
      f32x4 zz = {0.f, 0.f, 0.f, 0.f};
      zz = __builtin_amdgcn_mfma_f32_16x16x32_bf16(qa0, kb0, zz, 0, 0, 0);
      sc4[nc] = __builtin_amdgcn_mfma_f32_16x16x32_bf16(qa1, kb1, zz, 0, 0, 0);
    }

    u16* pw = Pf[w];
    #pragma unroll
    for (int r = 0; r < 4; ++r) {
      float v0 = ((m16 >> (r + 0))  & 1u) ? sc4[0][r] : NEG_INF;
      float v1 = ((m16 >> (r + 4))  & 1u) ? sc4[1][r] : NEG_INF;
      float v2 = ((m16 >> (r + 8))  & 1u) ? sc4[2][r] : NEG_INF;
      float v3 = ((m16 >> (r + 12)) & 1u) ? sc4[3][r] : NEG_INF;
      float mx = fmaxf(fmaxf(v0, v1), fmaxf(v2, v3));
      mx = fmaxf(mx, __shfl_xor(mx, 1));
      mx = fmaxf(mx, __shfl_xor(mx, 2));
      mx = fmaxf(mx, __shfl_xor(mx, 4));
      mx = fmaxf(mx, __shfl_xor(mx, 8));
      const float mn = fmaxf(mr[r], mx);
      const float alpha = (mn == NEG_INF) ? 1.f : __expf(mr[r] - mn);
      mr[r] = mn;
      const float p0 = (v0 == NEG_INF) ? 0.f : __expf(v0 - mn);
      const float p1 = (v1 == NEG_INF) ? 0.f : __expf(v1 - mn);
      const float p2 = (v2 == NEG_INF) ? 0.f : __expf(v2 - mn);
      const float p3 = (v3 == NEG_INF) ? 0.f : __expf(v3 - mn);
      float rs = p0 + p1 + p2 + p3;
      rs += __shfl_xor(rs, 1);
      rs += __shfl_xor(rs, 2);
      rs += __shfl_xor(rs, 4);
      rs += __shfl_xor(rs, 8);
      lr[r] = alpha * lr[r] + rs;
      o[0][r] = o[0][r] * alpha; o[1][r] = o[1][r] * alpha;
      o[2][r] = o[2][r] * alpha; o[3][r] = o[3][r] * alpha;
      // dropout (denominator uses undropped p; numerator uses p*dbit/0.9)
      const float pd0 = ((d16 >> (r + 0))  & 1u) ? p0 * (1.f / 0.9f) : 0.f;
      const float pd1 = ((d16 >> (r + 4))  & 1u) ? p1 * (1.f / 0.9f) : 0.f;
      const float pd2 = ((d16 >> (r + 8))  & 1u) ? p2 * (1.f / 0.9f) : 0.f;
      const float pd3 = ((d16 >> (r + 12)) & 1u) ? p3 * (1.f / 0.9f) : 0.f;
      // write P in A-frag layout: elem(m=qrow, k=key) -> chunk (k>>5)*64 + ((k>>3)&3)*16 + m
      const int hi = l >> 3, bq_ = quad * 4 + r, j = l & 7;
      pw[((hi) * 16 + bq_) * 8 + j]            = f2bf(pd0);   // keys  0..15
      pw[((2 + hi) * 16 + bq_) * 8 + j]        = f2bf(pd1);   // keys 16..31
      pw[(64 + hi * 16 + bq_) * 8 + j]         = f2bf(pd2);   // keys 32..47
      pw[(64 + (2 + hi) * 16 + bq_) * 8 + j]   = f2bf(pd3);   // keys 48..63
    }
    // same-wave LDS round-trip: read P as A-frags
    short8 pa0 = *(const short8*)(Pf[w] + lane * 8);
    short8 pa1 = *(const short8*)(Pf[w] + (64 + lane) * 8);
    #pragma unroll
    for (int nd = 0; nd < 4; ++nd) {
      short8 vb0 = *(const short8*)(Vf + ((nd * 2 + 0) * 64 + lane) * 8);
      short8 vb1 = *(const short8*)(Vf + ((nd * 2 + 1) * 64 + lane) * 8);
      o[nd] = __builtin_amdgcn_mfma_f32_16x16x32_bf16(pa0, vb0, o[nd], 0, 0, 0);
      o[nd] = __builtin_amdgcn_mfma_f32_16x16x32_bf16(pa1, vb1, o[nd], 0, 0, 0);
    }
  }

  const int b = bh >> 4, h = bh & 15;
  #pragma unroll
  for (int r = 0; r < 4; ++r) {
    const float inv = 1.f / lr[r];
    const int qrow = qb * 64 + w * 16 + quad * 4 + r;
    const u32 ob = (u32)(b * S_LEN + qrow) * DMODEL + h * DK;
    ctx[ob + 0  + l] = f2bf(o[0][r] * inv);
    ctx[ob + 16 + l] = f2bf(o[1][r] * inv);
    ctx[ob + 32 + l] = f2bf(o[2][r] * inv);
    ctx[ob + 48 + l] = f2bf(o[3][r] * inv);
  }
}

// ---------------- output projection (ctx @ Wo.T + bo), bf16 A, fp32 B-in, fp32 out ----------------
__global__ __launch_bounds__(256) void oproj_kernel(
    const u16* __restrict__ X, const float* __restrict__ W, const float* __restrict__ bias,
    float* __restrict__ out)
{
  const int m0 = blockIdx.x * 64, n0 = blockIdx.y * 64;
  const int tid = threadIdx.x, w = tid >> 6, lane = tid & 63, l = lane & 15, quad = lane >> 4;

  __shared__ __align__(16) u16 lsA[2048], lsB[2048];

  const int srow = tid >> 2, skp = tid & 3;
  const int sc = ((srow >> 4) * 64 + skp * 16 + (srow & 15)) * 8;
  const u16*  gA = X + (u32)(m0 + srow) * DMODEL + skp * 8;
  const float* gB = W + (u32)(n0 + srow) * DMODEL + skp * 8;

  f32x4 acc[2][2] = {};
  const int mh = (w >> 1) * 2, nh = (w & 1) * 2;

  for (int k0 = 0; k0 < DMODEL; k0 += 32) {
    short8 av  = *(const short8*)(gA + k0);
    short8 bv8 = cvt8(*(const float4*)(gB + k0), *(const float4*)(gB + k0 + 4));
    __syncthreads();
    *(short8*)(lsA + sc) = av;
    *(short8*)(lsB + sc) = bv8;
    __syncthreads();
    short8 a0 = *(const short8*)(lsA + ((mh + 0) * 64 + lane) * 8);
    short8 a1 = *(const short8*)(lsA + ((mh + 1) * 64 + lane) * 8);
    short8 b0 = *(const short8*)(lsB + ((nh + 0) * 64 + lane) * 8);
    short8 b1 = *(const short8*)(lsB + ((nh + 1) * 64 + lane) * 8);
    acc[0][0] = __builtin_amdgcn_mfma_f32_16x16x32_bf16(a0, b0, acc[0][0], 0, 0, 0);
    acc[0][1] = __builtin_amdgcn_mfma_f32_16x16x32_bf16(a0, b1, acc[0][1], 0, 0, 0);
    acc[1][0] = __builtin_amdgcn_mfma_f32_16x16x32_bf16(a1, b0, acc[1][0], 0, 0, 0);
    acc[1][1] = __builtin_amdgcn_mfma_f32_16x16x32_bf16(a1, b1, acc[1][1], 0, 0, 0);
  }

  #pragma unroll
  for (int ma = 0; ma < 2; ++ma) {
    #pragma unroll
    for (int nb = 0; nb < 2; ++nb) {
      const int n = n0 + (nh + nb) * 16 + l;
      const float bval = bias[n];
      #pragma unroll
      for (int r = 0; r < 4; ++r) {
        const int m = m0 + (mh + ma) * 16 + quad * 4 + r;
        out[(u32)m * DMODEL + n] = acc[ma][nb][r] + bval;
      }
    }
  }
}

extern "C" void kernel_launch(void* const* d_in, const int* in_sizes, int n_in,
                              void* d_out, int out_size, void* d_ws, size_t ws_size,
                              hipStream_t stream) {
  (void)in_sizes; (void)n_in; (void)out_size; (void)ws_size;
  const float* q  = (const float*)d_in[0];
  const float* k  = (const float*)d_in[1];
  const float* v  = (const float*)d_in[2];
  const float* Wq = (const float*)d_in[3];
  const float* bq = (const float*)d_in[4];
  const float* Wk = (const float*)d_in[5];
  const float* bk = (const float*)d_in[6];
  const float* Wv = (const float*)d_in[7];
  const float* bv = (const float*)d_in[8];
  const float* Wo = (const float*)d_in[9];
  const float* bo = (const float*)d_in[10];

  char* ws = (char*)d_ws;
  u16* Qs   = (u16*)(ws);                 // [bh][s][dk] bf16, pre-scaled 1/8 (16 MB)
  u16* Ks   = (u16*)(ws + 16777216);      // [bh][s][dk]
  u16* Vts  = (u16*)(ws + 33554432);      // [bh][dk][s]  (transposed)
  u16* ctx  = (u16*)(ws + 50331648);      // [b][s][h*dk]  (total ws: 64 MB)

  proj_kernel<<<dim3(128, 16, 3), 256, 0, stream>>>(q, k, v, Wq, Wk, Wv,
                                                    bq, bk, bv, Qs, Ks, Vts);
  attn_kernel<<<dim3(32, 64), 256, 0, stream>>>(Qs, Ks, Vts, ctx);
  oproj_kernel<<<dim3(128, 16), 256, 0, stream>>>(ctx, Wo, bo, (float*)d_out);
}